// Round 6
// baseline (482.443 us; speedup 1.0000x reference)
//
#include <hip/hip_runtime.h>
#include <hip/hip_bf16.h>

#define NNODES 50000
#define NEDGES 600000
#define NGRAPHS 512
#define BN_EPS 1e-5f

typedef short bf16x8 __attribute__((ext_vector_type(8)));
typedef float f32x4 __attribute__((ext_vector_type(4)));

// split fp32 -> hi/lo bf16 (RNE); hi+lo carries ~16 mantissa bits
__device__ __forceinline__ void bf_split(float x, ushort& h, ushort& l) {
    __hip_bfloat16 bh = __float2bfloat16(x);
    float r = x - __bfloat162float(bh);
    __hip_bfloat16 bl = __float2bfloat16(r);
    h = __builtin_bit_cast(ushort, bh);
    l = __builtin_bit_cast(ushort, bl);
}

// ---------------------------------------------------------------- CSR build
__global__ __launch_bounds__(256) void hist_kernel(const int* __restrict__ dst,
                                                   int* __restrict__ counts, int E) {
    int i = blockIdx.x * 256 + threadIdx.x;
    if (i < E) atomicAdd(&counts[dst[i]], 1);
}

__global__ __launch_bounds__(256) void scan1_kernel(const int* __restrict__ counts,
                                                    int* __restrict__ partials, int n) {
    __shared__ int s[256];
    int i = blockIdx.x * 256 + threadIdx.x;
    int v = (i < n) ? counts[i] : 0;
    s[threadIdx.x] = v;
    __syncthreads();
    for (int off = 128; off > 0; off >>= 1) {
        if (threadIdx.x < off) s[threadIdx.x] += s[threadIdx.x + off];
        __syncthreads();
    }
    if (threadIdx.x == 0) partials[blockIdx.x] = s[0];
}

__global__ __launch_bounds__(256) void scan2_kernel(int* __restrict__ partials, int nb,
                                                    int* __restrict__ row_ptr, int total) {
    __shared__ int s[256];
    int t = threadIdx.x;
    int v = (t < nb) ? partials[t] : 0;
    s[t] = v;
    __syncthreads();
    for (int off = 1; off < 256; off <<= 1) {
        int nv = (t >= off) ? s[t - off] : 0;
        __syncthreads();
        s[t] += nv;
        __syncthreads();
    }
    if (t < nb) partials[t] = s[t] - v;   // exclusive
    if (t == 0) row_ptr[NNODES] = total;
}

__global__ __launch_bounds__(256) void scan3_kernel(const int* __restrict__ counts,
                                                    const int* __restrict__ partials,
                                                    int* __restrict__ row_ptr,
                                                    int* __restrict__ cursor, int n) {
    __shared__ int s[256];
    int i = blockIdx.x * 256 + threadIdx.x;
    int v = (i < n) ? counts[i] : 0;
    s[threadIdx.x] = v;
    __syncthreads();
    for (int off = 1; off < 256; off <<= 1) {
        int nv = (threadIdx.x >= (unsigned)off) ? s[threadIdx.x - off] : 0;
        __syncthreads();
        s[threadIdx.x] += nv;
        __syncthreads();
    }
    if (i < n) {
        int ex = partials[blockIdx.x] + s[threadIdx.x] - v;  // exclusive
        row_ptr[i] = ex;
        cursor[i] = ex;
    }
}

__global__ __launch_bounds__(256) void scatter_kernel(const int* __restrict__ src,
                                                      const int* __restrict__ dst,
                                                      int* __restrict__ cursor,
                                                      int* __restrict__ esrc, int E) {
    int i = blockIdx.x * 256 + threadIdx.x;
    if (i < E) {
        int p = atomicAdd(&cursor[dst[i]], 1);
        esrc[p] = src[i];
    }
}

// ---------------------------------------------------------------- W prep
// W[k][n] fp32 -> transposed bf16 hi/lo planes [n][k].
__global__ __launch_bounds__(256) void wsplit_kernel(
    const float* W0, const float* W1, const float* W2, const float* W3,
    const float* W4, const float* W5, ushort* __restrict__ hi, ushort* __restrict__ lo) {
    const float* Ws[6] = {W0, W1, W2, W3, W4, W5};
    const float* W = Ws[blockIdx.y];
    ushort* h = hi + (size_t)blockIdx.y * 16384;
    ushort* l = lo + (size_t)blockIdx.y * 16384;
#pragma unroll
    for (int i = 0; i < 4; i++) {
        int idx = blockIdx.x * 1024 + i * 256 + threadIdx.x;
        int n = idx >> 7, k = idx & 127;
        ushort hh, ll;
        bf_split(W[k * 128 + n], hh, ll);
        h[n * 128 + k] = hh;
        l[n * 128 + k] = ll;
    }
}

// ------------------------------------------------------------ fused layer
// out = act( BN_ReLU( (x + sum_nbr x) @ W1 ) @ W2 + b2 ) for 64 nodes/block.
// Phase 0: gather (2 nodes per wave-pass, 32 lanes x float4/row), exact fp32
//   sum, bf_split -> A hi/lo planes in LDS (stride 136 ushorts: fragment
//   reads land 8 lanes per 4-bank group = perfectly balanced; 2-way = free).
// Phase 1: A @ W1 (split-bf16, 3 MFMA terms), W1 frags direct from global
//   (L2-hot). BN+ReLU -> H hi/lo planes into the SAME LDS (A dead).
// Phase 2: H @ W2 -> +b2 (,ReLU) -> fp32 out. Only 3 barriers.
// LDS 34.8KB -> 4 blocks/CU = 16 waves/CU; gather of some blocks overlaps
// MFMA of co-resident blocks (m114 co-schedule) - the R5 structure couldn't.
#define HSTR 136   // LDS row stride (ushorts)
#define PPLANE 8704  // 64*136
template <bool RELU_OUT>
__global__ __launch_bounds__(256) void layer_kernel(
    const float* __restrict__ xin, const int* __restrict__ rp,
    const int* __restrict__ esrc,
    const ushort* __restrict__ W1hi, const ushort* __restrict__ W1lo,
    const ushort* __restrict__ W2hi, const ushort* __restrict__ W2lo,
    const float* __restrict__ b1, const float* __restrict__ gm,
    const float* __restrict__ bt, const float* __restrict__ rm,
    const float* __restrict__ rv, const float* __restrict__ b2,
    float* __restrict__ out, int M) {
    __shared__ __align__(16) ushort smem[2 * PPLANE];
#define SH(p_, o_) smem[(p_)*PPLANE + (o_)]
    const int t = threadIdx.x;
    const int lane = t & 63;
    const int wv = t >> 6;
    const int wr = wv >> 1, wc = wv & 1;     // 2x2 wave grid: 32 rows x 64 cols
    const int row0 = blockIdx.x * 64;
    const int g = lane >> 4, c = lane & 15;
    const int q = lane & 31;

    // ---------------- phase 0: gather + split into LDS A planes
    const float4* x4 = (const float4*)xin;
#pragma unroll 1
    for (int pass = 0; pass < 8; pass++) {
        int nt = wv * 16 + pass * 2 + (lane >> 5);
        int node = row0 + nt;
        float4 acc = make_float4(0.f, 0.f, 0.f, 0.f);
        if (node < M) {
            acc = x4[(size_t)node * 32 + q];   // self term (eps=0)
            int beg = rp[node], end = rp[node + 1];
            int e = beg;
            for (; e + 4 <= end; e += 4) {
                int i0 = esrc[e], i1 = esrc[e + 1], i2 = esrc[e + 2], i3 = esrc[e + 3];
                float4 v0 = x4[(size_t)i0 * 32 + q];
                float4 v1 = x4[(size_t)i1 * 32 + q];
                float4 v2 = x4[(size_t)i2 * 32 + q];
                float4 v3 = x4[(size_t)i3 * 32 + q];
                acc.x += (v0.x + v1.x) + (v2.x + v3.x);
                acc.y += (v0.y + v1.y) + (v2.y + v3.y);
                acc.z += (v0.z + v1.z) + (v2.z + v3.z);
                acc.w += (v0.w + v1.w) + (v2.w + v3.w);
            }
            for (; e < end; e++) {
                int i0 = esrc[e];
                float4 v = x4[(size_t)i0 * 32 + q];
                acc.x += v.x; acc.y += v.y; acc.z += v.z; acc.w += v.w;
            }
        }
        ushort4 hh, ll;
        bf_split(acc.x, hh.x, ll.x);
        bf_split(acc.y, hh.y, ll.y);
        bf_split(acc.z, hh.z, ll.z);
        bf_split(acc.w, hh.w, ll.w);
        *(ushort4*)&SH(0, nt * HSTR + q * 4) = hh;
        *(ushort4*)&SH(1, nt * HSTR + q * 4) = ll;
    }
    __syncthreads();

    // ---------------- phase 1: A @ W1
    f32x4 acc[2][4];
#pragma unroll
    for (int i = 0; i < 2; i++)
#pragma unroll
        for (int j = 0; j < 4; j++) acc[i][j] = (f32x4){0.f, 0.f, 0.f, 0.f};

#pragma unroll
    for (int kb = 0; kb < 4; kb++) {
        bf16x8 bh[4], bl[4];
#pragma unroll
        for (int ct = 0; ct < 4; ct++) {
            const size_t wo = (size_t)(wc * 64 + ct * 16 + c) * 128 + kb * 32 + g * 8;
            bh[ct] = *(const bf16x8*)(W1hi + wo);
            bl[ct] = *(const bf16x8*)(W1lo + wo);
        }
        bf16x8 ah[2], al[2];
#pragma unroll
        for (int rt = 0; rt < 2; rt++) {
            int off = (wr * 32 + rt * 16 + c) * HSTR + kb * 32 + g * 8;
            ah[rt] = *(bf16x8*)&SH(0, off);
            al[rt] = *(bf16x8*)&SH(1, off);
        }
#pragma unroll
        for (int rt = 0; rt < 2; rt++)
#pragma unroll
            for (int ct = 0; ct < 4; ct++) {
                acc[rt][ct] = __builtin_amdgcn_mfma_f32_16x16x32_bf16(ah[rt], bh[ct], acc[rt][ct], 0, 0, 0);
                acc[rt][ct] = __builtin_amdgcn_mfma_f32_16x16x32_bf16(ah[rt], bl[ct], acc[rt][ct], 0, 0, 0);
                acc[rt][ct] = __builtin_amdgcn_mfma_f32_16x16x32_bf16(al[rt], bh[ct], acc[rt][ct], 0, 0, 0);
            }
    }
    __syncthreads();   // all A reads done -> H may overwrite

    // ---------------- BN + ReLU -> H planes (same LDS)
    {
        float cs[4], ca[4];
#pragma unroll
        for (int ct = 0; ct < 4; ct++) {
            int n = wc * 64 + ct * 16 + c;
            float s = gm[n] * rsqrtf(rv[n] + BN_EPS);
            cs[ct] = s;
            ca[ct] = (b1[n] - rm[n]) * s + bt[n];
        }
#pragma unroll
        for (int rt = 0; rt < 2; rt++)
#pragma unroll
            for (int r = 0; r < 4; r++) {
                int row = wr * 32 + rt * 16 + g * 4 + r;
#pragma unroll
                for (int ct = 0; ct < 4; ct++) {
                    int col = wc * 64 + ct * 16 + c;
                    float v = fmaxf(acc[rt][ct][r] * cs[ct] + ca[ct], 0.f);
                    ushort hh, ll;
                    bf_split(v, hh, ll);
                    SH(0, row * HSTR + col) = hh;
                    SH(1, row * HSTR + col) = ll;
                }
            }
    }
    __syncthreads();

    // ---------------- phase 2: H @ W2 (H read-only: no barriers in loop)
#pragma unroll
    for (int i = 0; i < 2; i++)
#pragma unroll
        for (int j = 0; j < 4; j++) acc[i][j] = (f32x4){0.f, 0.f, 0.f, 0.f};

#pragma unroll
    for (int kb = 0; kb < 4; kb++) {
        bf16x8 bh[4], bl[4];
#pragma unroll
        for (int ct = 0; ct < 4; ct++) {
            const size_t wo = (size_t)(wc * 64 + ct * 16 + c) * 128 + kb * 32 + g * 8;
            bh[ct] = *(const bf16x8*)(W2hi + wo);
            bl[ct] = *(const bf16x8*)(W2lo + wo);
        }
        bf16x8 ah[2], al[2];
#pragma unroll
        for (int rt = 0; rt < 2; rt++) {
            int off = (wr * 32 + rt * 16 + c) * HSTR + kb * 32 + g * 8;
            ah[rt] = *(bf16x8*)&SH(0, off);
            al[rt] = *(bf16x8*)&SH(1, off);
        }
#pragma unroll
        for (int rt = 0; rt < 2; rt++)
#pragma unroll
            for (int ct = 0; ct < 4; ct++) {
                acc[rt][ct] = __builtin_amdgcn_mfma_f32_16x16x32_bf16(ah[rt], bh[ct], acc[rt][ct], 0, 0, 0);
                acc[rt][ct] = __builtin_amdgcn_mfma_f32_16x16x32_bf16(ah[rt], bl[ct], acc[rt][ct], 0, 0, 0);
                acc[rt][ct] = __builtin_amdgcn_mfma_f32_16x16x32_bf16(al[rt], bh[ct], acc[rt][ct], 0, 0, 0);
            }
    }

    // ---------------- epilogue: +b2 (, ReLU) -> fp32
    float ca2[4];
#pragma unroll
    for (int ct = 0; ct < 4; ct++) ca2[ct] = b2[wc * 64 + ct * 16 + c];
#pragma unroll
    for (int rt = 0; rt < 2; rt++)
#pragma unroll
        for (int r = 0; r < 4; r++) {
            int row = row0 + wr * 32 + rt * 16 + g * 4 + r;
            if (row < M) {
#pragma unroll
                for (int ct = 0; ct < 4; ct++) {
                    int col = wc * 64 + ct * 16 + c;
                    float v = acc[rt][ct][r] + ca2[ct];
                    if (RELU_OUT) v = fmaxf(v, 0.f);
                    out[(size_t)row * 128 + col] = v;
                }
            }
        }
#undef SH
}

// ----------------------------------------------------------------- pooling
__global__ __launch_bounds__(384) void pool_kernel(const float* __restrict__ x1,
                                                   const float* __restrict__ x2,
                                                   const float* __restrict__ x3,
                                                   const int* __restrict__ batch,
                                                   float* __restrict__ pooled, int n) {
    __shared__ int bs[128];
    int b0 = blockIdx.x * 128;
    int t = threadIdx.x;
    int rows = n - b0; if (rows > 128) rows = 128;
    for (int i = t; i < rows; i += 384) bs[i] = batch[b0 + i];
    __syncthreads();
    const float* src = (t < 128) ? x1 : ((t < 256) ? x2 : x3);
    int ch = t & 127;
    int gcur = bs[0];
    float acc = 0.f;
#pragma unroll 8
    for (int r = 0; r < rows; r++) {
        int gg = bs[r];
        if (gg != gcur) {                       // block-uniform branch
            atomicAdd(&pooled[gcur * 384 + t], acc);
            acc = 0.f;
            gcur = gg;
        }
        acc += src[(size_t)(b0 + r) * 128 + ch];
    }
    atomicAdd(&pooled[gcur * 384 + t], acc);
}

__global__ __launch_bounds__(128) void final_kernel(const float* __restrict__ pooled,
                                                    const int* __restrict__ batch,
                                                    const float* __restrict__ W,
                                                    const float* __restrict__ b,
                                                    float* __restrict__ out, int n) {
    __shared__ float ps[384];
    int gph = blockIdx.x, t = threadIdx.x;
    int lo1 = 0, hi1 = n;
    while (lo1 < hi1) { int mid = (lo1 + hi1) >> 1; if (batch[mid] < gph) lo1 = mid + 1; else hi1 = mid; }
    int start = lo1;
    int lo2 = start, hi2 = n;
    while (lo2 < hi2) { int mid = (lo2 + hi2) >> 1; if (batch[mid] < gph + 1) lo2 = mid + 1; else hi2 = mid; }
    int cnt = lo2 - start;
    float inv = 1.f / (float)(cnt > 0 ? cnt : 1);
    for (int i = t; i < 384; i += 128) ps[i] = pooled[gph * 384 + i] * inv;
    __syncthreads();
    float acc = b[t];
#pragma unroll 8
    for (int k = 0; k < 384; k++) acc += ps[k] * W[k * 128 + t];
    out[gph * 128 + t] = acc;
}

// ------------------------------------------------------------------ launch
extern "C" void kernel_launch(void* const* d_in, const int* in_sizes, int n_in,
                              void* d_out, int out_size, void* d_ws, size_t ws_size,
                              hipStream_t stream) {
    const float* x     = (const float*)d_in[0];
    const int*   edge  = (const int*)d_in[1];
    const int*   batch = (const int*)d_in[2];
    const float* p[32];
    for (int i = 0; i < n_in && i < 32; i++) p[i] = (const float*)d_in[i];
    const float* lin_W = p[27];
    const float* lin_b = p[28];

    char* w = (char*)d_ws;
    auto alloc = [&](size_t bytes) { void* r = (void*)w; w += (bytes + 255) & ~(size_t)255; return r; };
    const size_t PL = (size_t)NNODES * 128;
    float* x1     = (float*)alloc(PL * 4);
    float* x2b    = (float*)alloc(PL * 4);
    float* x3b    = (float*)alloc(PL * 4);
    float* pooled = (float*)alloc((size_t)NGRAPHS * 384 * 4);
    int* counts   = (int*)alloc((size_t)NNODES * 4);
    int* cursor   = (int*)alloc((size_t)NNODES * 4);
    int* row_ptr  = (int*)alloc((size_t)(NNODES + 1) * 4);
    int* esrc     = (int*)alloc((size_t)NEDGES * 4);
    int* partials = (int*)alloc(256 * 4);
    ushort* wt_hi = (ushort*)alloc((size_t)6 * 16384 * 2);
    ushort* wt_lo = (ushort*)alloc((size_t)6 * 16384 * 2);

    const int* src = edge;
    const int* dst = edge + NEDGES;

    // --- weight split/transpose (6 matrices)
    wsplit_kernel<<<dim3(16, 6), 256, 0, stream>>>(p[3], p[9], p[11], p[17], p[19], p[25],
                                                   wt_hi, wt_lo);

    // --- CSR build (reused by all 3 layers)
    hipMemsetAsync(counts, 0, (size_t)NNODES * 4, stream);
    hipMemsetAsync(pooled, 0, (size_t)NGRAPHS * 384 * 4, stream);
    hist_kernel<<<(NEDGES + 255) / 256, 256, 0, stream>>>(dst, counts, NEDGES);
    int nb = (NNODES + 255) / 256;  // 196
    scan1_kernel<<<nb, 256, 0, stream>>>(counts, partials, NNODES);
    scan2_kernel<<<1, 256, 0, stream>>>(partials, nb, row_ptr, NEDGES);
    scan3_kernel<<<nb, 256, 0, stream>>>(counts, partials, row_ptr, cursor, NNODES);
    scatter_kernel<<<(NEDGES + 255) / 256, 256, 0, stream>>>(src, dst, cursor, esrc, NEDGES);

    // --- 3 fused GIN layers (gather + MLP in one kernel)
    int grid = (NNODES + 63) / 64;   // 782
    const float* xin = x;
    float* fouts[3] = {x1, x2b, x3b};
    for (int li = 0; li < 3; li++) {
        const float* b1 = p[4 + 8 * li];
        const float* gm = p[5 + 8 * li];
        const float* bt = p[6 + 8 * li];
        const float* rm = p[7 + 8 * li];
        const float* rv = p[8 + 8 * li];
        const float* b2 = p[10 + 8 * li];
        const ushort* w1h = wt_hi + (size_t)(2 * li) * 16384;
        const ushort* w1l = wt_lo + (size_t)(2 * li) * 16384;
        const ushort* w2h = wt_hi + (size_t)(2 * li + 1) * 16384;
        const ushort* w2l = wt_lo + (size_t)(2 * li + 1) * 16384;

        if (li < 2)
            layer_kernel<true><<<grid, 256, 0, stream>>>(xin, row_ptr, esrc,
                                                         w1h, w1l, w2h, w2l,
                                                         b1, gm, bt, rm, rv, b2,
                                                         fouts[li], NNODES);
        else
            layer_kernel<false><<<grid, 256, 0, stream>>>(xin, row_ptr, esrc,
                                                          w1h, w1l, w2h, w2l,
                                                          b1, gm, bt, rm, rv, b2,
                                                          fouts[li], NNODES);
        xin = fouts[li];
    }

    // --- JK-concat mean pool + final linear
    pool_kernel<<<(NNODES + 127) / 128, 384, 0, stream>>>(x1, x2b, x3b, batch, pooled, NNODES);
    final_kernel<<<NGRAPHS, 128, 0, stream>>>(pooled, batch, lin_W, lin_b, (float*)d_out, NNODES);
}